// Round 3
// baseline (457.539 us; speedup 1.0000x reference)
//
#include <hip/hip_runtime.h>
#include <math.h>

#define BB 16
#define LL 512
#define DD 768
#define HH 12
#define DHH 64
#define SPDD 5
#define MM (BB*LL)   // 8192
#define LN_EPS 1e-5f
#define CLAMP_MINV 1e-6f

typedef __attribute__((ext_vector_type(8))) short bf8_t;
typedef __attribute__((ext_vector_type(4))) float f4_t;

__device__ __forceinline__ short f2bf(float x) {
    unsigned u = __builtin_bit_cast(unsigned, x);
    unsigned r = (u + 0x7FFFu + ((u >> 16) & 1u)) >> 16;
    return (short)r;
}
__device__ __forceinline__ float bf2f(short s) {
    unsigned u = ((unsigned)(unsigned short)s) << 16;
    return __builtin_bit_cast(float, u);
}

__device__ __forceinline__ void gld16(const short* g, short* l) {
    __builtin_amdgcn_global_load_lds(
        (const __attribute__((address_space(1))) unsigned int*)g,
        (__attribute__((address_space(3))) unsigned int*)l,
        16, 0, 0);
}

// ---------------- block reduce (256 threads, wave64) ------------------------
__device__ __forceinline__ float block_sum(float v, float* red, int tid) {
    #pragma unroll
    for (int off = 32; off; off >>= 1) v += __shfl_down(v, off, 64);
    __syncthreads();
    if ((tid & 63) == 0) red[tid >> 6] = v;
    __syncthreads();
    return red[0] + red[1] + red[2] + red[3];
}

// ---------------- prep: input cast + weight transpose -----------------------
// blocks [0,3072): aqk = bf16(tgt+qpos), av = bf16(tgt)
// blocks [3072,3648): Wt[n][k] = bf16(W[k][n]) for 4 weights
__global__ __launch_bounds__(256) void prep_kernel(
    const float* __restrict__ tgt, const float* __restrict__ qpos,
    const float* __restrict__ W0, const float* __restrict__ W1,
    const float* __restrict__ W2, const float* __restrict__ W3,
    short* __restrict__ aqk, short* __restrict__ av,
    short* __restrict__ O0, short* __restrict__ O1,
    short* __restrict__ O2, short* __restrict__ O3)
{
    __shared__ float T[64][65];
    const int t = blockIdx.x;
    if (t < 3072) {
        // ---- input cast ----
        const size_t base = ((size_t)t * 256 + threadIdx.x) * 8;
        const float4 t0 = *(const float4*)(tgt + base);
        const float4 t1 = *(const float4*)(tgt + base + 4);
        const float4 p0 = *(const float4*)(qpos + base);
        const float4 p1 = *(const float4*)(qpos + base + 4);
        short v[8], q[8];
        v[0] = f2bf(t0.x); v[1] = f2bf(t0.y); v[2] = f2bf(t0.z); v[3] = f2bf(t0.w);
        v[4] = f2bf(t1.x); v[5] = f2bf(t1.y); v[6] = f2bf(t1.z); v[7] = f2bf(t1.w);
        q[0] = f2bf(t0.x + p0.x); q[1] = f2bf(t0.y + p0.y);
        q[2] = f2bf(t0.z + p0.z); q[3] = f2bf(t0.w + p0.w);
        q[4] = f2bf(t1.x + p1.x); q[5] = f2bf(t1.y + p1.y);
        q[6] = f2bf(t1.z + p1.z); q[7] = f2bf(t1.w + p1.w);
        *(bf8_t*)(av + base)  = *(bf8_t*)v;
        *(bf8_t*)(aqk + base) = *(bf8_t*)q;
    } else {
        // ---- weight transpose + cast ----
        const int wt = t - 3072;                // 0..575
        const int wi = wt / 144;
        const int rem = wt % 144;
        const float* W; short* O;
        switch (wi) {
            case 0: W = W0; O = O0; break;
            case 1: W = W1; O = O1; break;
            case 2: W = W2; O = O2; break;
            default: W = W3; O = O3; break;
        }
        const int n0 = (rem % 12) * 64, k0 = (rem / 12) * 64;
        const int tid = threadIdx.x;
        {
            const int kk = tid >> 4, nv = (tid & 15) * 4;
            #pragma unroll
            for (int i = 0; i < 4; ++i) {
                const int k = kk + i * 16;
                const float4 v = *(const float4*)(W + (size_t)(k0 + k) * DD + n0 + nv);
                T[k][nv + 0] = v.x; T[k][nv + 1] = v.y;
                T[k][nv + 2] = v.z; T[k][nv + 3] = v.w;
            }
        }
        __syncthreads();
        {
            const int n = tid >> 2, kc = (tid & 3) * 16;
            short tmp[16];
            #pragma unroll
            for (int i = 0; i < 16; ++i) tmp[i] = f2bf(T[kc + i][n]);
            short* dst = O + (size_t)(n0 + n) * DD + k0 + kc;
            *(bf8_t*)dst       = *(bf8_t*)tmp;
            *(bf8_t*)(dst + 8) = *(bf8_t*)(tmp + 8);
        }
    }
}

// ---------------- fused Q/K/V bf16 MFMA GEMM (XCD-swizzled) -----------------
__global__ __launch_bounds__(256) void gemm_qkv(
    const short* __restrict__ Aqk, const short* __restrict__ Av,
    const short* __restrict__ Wq, const float* __restrict__ bq, short* __restrict__ oq,
    const short* __restrict__ Wk, const float* __restrict__ bk, short* __restrict__ ok,
    const short* __restrict__ Wv, const float* __restrict__ bv, short* __restrict__ ov)
{
    __shared__ short As[128 * 64];
    __shared__ short Bs[128 * 64];
    // XCD remap: id%8 = XCD (round-robin); give each XCD 8 contiguous m-blocks
    const int id = blockIdx.y * 18 + blockIdx.x;
    const int xcd = id & 7, j = id >> 3;          // j: 0..143
    const int by = xcd * 8 + j / 18;
    const int gx = j % 18;
    const int seg = gx / 6;
    const int bx = gx % 6;
    const short* A  = (seg == 2) ? Av : Aqk;
    const short* Wt = (seg == 0) ? Wq : (seg == 1) ? Wk : Wv;
    const float* bias = (seg == 0) ? bq : (seg == 1) ? bk : bv;
    short* out = (seg == 0) ? oq : (seg == 1) ? ok : ov;

    const int n0 = bx * 128, m0 = by * 128;
    const int tid = threadIdx.x;
    const int w = tid >> 6, lane = tid & 63;
    const int quad = lane >> 4, l16 = lane & 15;
    const int wm = w & 1, wn = w >> 1;
    const int sr = w * 8 + (lane >> 3);
    const int sp = lane & 7;

    f4_t acc[4][4];
    #pragma unroll
    for (int i = 0; i < 4; ++i)
        #pragma unroll
        for (int jj = 0; jj < 4; ++jj) acc[i][jj] = (f4_t){0.f, 0.f, 0.f, 0.f};

    for (int k0 = 0; k0 < DD; k0 += 64) {
        __syncthreads();
        #pragma unroll
        for (int ra = 0; ra < 4; ++ra) {
            const int r = sr + ra * 32;
            const int c = sp ^ (r & 7);
            const int ldso = ra * 2048 + w * 512 + lane * 8;
            gld16(A  + (size_t)(m0 + r) * DD + k0 + c * 8, As + ldso);
            gld16(Wt + (size_t)(n0 + r) * DD + k0 + c * 8, Bs + ldso);
        }
        __syncthreads();
        #pragma unroll
        for (int s = 0; s < 2; ++s) {
            bf8_t a[4], b[4];
            #pragma unroll
            for (int i = 0; i < 4; ++i) {
                const int rA = wm * 64 + i * 16 + l16;
                const int pA = (s * 4 + quad) ^ (rA & 7);
                a[i] = *(const bf8_t*)(As + rA * 64 + pA * 8);
                const int rB = wn * 64 + i * 16 + l16;
                const int pB = (s * 4 + quad) ^ (rB & 7);
                b[i] = *(const bf8_t*)(Bs + rB * 64 + pB * 8);
            }
            #pragma unroll
            for (int i = 0; i < 4; ++i)
                #pragma unroll
                for (int jj = 0; jj < 4; ++jj)
                    acc[i][jj] = __builtin_amdgcn_mfma_f32_16x16x32_bf16(a[i], b[jj], acc[i][jj], 0, 0, 0);
        }
    }

    float bvv[4];
    #pragma unroll
    for (int jj = 0; jj < 4; ++jj) bvv[jj] = bias[n0 + wn * 64 + jj * 16 + l16];
    #pragma unroll
    for (int i = 0; i < 4; ++i) {
        #pragma unroll
        for (int jj = 0; jj < 4; ++jj) {
            const int n = n0 + wn * 64 + jj * 16 + l16;
            #pragma unroll
            for (int r = 0; r < 4; ++r) {
                const int m = m0 + wm * 64 + i * 16 + quad * 4 + r;
                const float val = acc[i][jj][r] + bvv[jj];
                const int b_ = m >> 9, l = m & 511;
                const int h = n >> 6, d = n & 63;
                if (seg < 2)
                    out[(((size_t)(b_ * HH + h)) * LL + l) * DHH + d] = f2bf(val);
                else
                    out[(((size_t)(b_ * HH + h)) * DHH + d) * LL + l] = f2bf(val);
            }
        }
    }
}

// ---------------- O-projection GEMM (XCD-swizzled, fp32 out) ----------------
__global__ __launch_bounds__(256) void gemm_o(
    const short* __restrict__ A, const short* __restrict__ Wt,
    const float* __restrict__ bias, float* __restrict__ out)
{
    __shared__ short As[128 * 64];
    __shared__ short Bs[128 * 64];
    const int id = blockIdx.y * 6 + blockIdx.x;
    const int xcd = id & 7, j = id >> 3;          // j: 0..47
    const int by = xcd * 8 + j / 6;
    const int bx = j % 6;
    const int n0 = bx * 128, m0 = by * 128;
    const int tid = threadIdx.x;
    const int w = tid >> 6, lane = tid & 63;
    const int quad = lane >> 4, l16 = lane & 15;
    const int wm = w & 1, wn = w >> 1;
    const int sr = w * 8 + (lane >> 3);
    const int sp = lane & 7;

    f4_t acc[4][4];
    #pragma unroll
    for (int i = 0; i < 4; ++i)
        #pragma unroll
        for (int jj = 0; jj < 4; ++jj) acc[i][jj] = (f4_t){0.f, 0.f, 0.f, 0.f};

    for (int k0 = 0; k0 < DD; k0 += 64) {
        __syncthreads();
        #pragma unroll
        for (int ra = 0; ra < 4; ++ra) {
            const int r = sr + ra * 32;
            const int c = sp ^ (r & 7);
            const int ldso = ra * 2048 + w * 512 + lane * 8;
            gld16(A  + (size_t)(m0 + r) * DD + k0 + c * 8, As + ldso);
            gld16(Wt + (size_t)(n0 + r) * DD + k0 + c * 8, Bs + ldso);
        }
        __syncthreads();
        #pragma unroll
        for (int s = 0; s < 2; ++s) {
            bf8_t a[4], b[4];
            #pragma unroll
            for (int i = 0; i < 4; ++i) {
                const int rA = wm * 64 + i * 16 + l16;
                const int pA = (s * 4 + quad) ^ (rA & 7);
                a[i] = *(const bf8_t*)(As + rA * 64 + pA * 8);
                const int rB = wn * 64 + i * 16 + l16;
                const int pB = (s * 4 + quad) ^ (rB & 7);
                b[i] = *(const bf8_t*)(Bs + rB * 64 + pB * 8);
            }
            #pragma unroll
            for (int i = 0; i < 4; ++i)
                #pragma unroll
                for (int jj = 0; jj < 4; ++jj)
                    acc[i][jj] = __builtin_amdgcn_mfma_f32_16x16x32_bf16(a[i], b[jj], acc[i][jj], 0, 0, 0);
        }
    }

    float bvv[4];
    #pragma unroll
    for (int jj = 0; jj < 4; ++jj) bvv[jj] = bias[n0 + wn * 64 + jj * 16 + l16];
    #pragma unroll
    for (int i = 0; i < 4; ++i)
        #pragma unroll
        for (int jj = 0; jj < 4; ++jj) {
            const int n = n0 + wn * 64 + jj * 16 + l16;
            #pragma unroll
            for (int r = 0; r < 4; ++r) {
                const int m = m0 + wm * 64 + i * 16 + quad * 4 + r;
                out[(size_t)m * DD + n] = acc[i][jj][r] + bvv[jj];
            }
        }
}

// ---------------- flash-style MFMA attention with fused spatial bias --------
// 8-wave blocks (512 thr), Q-tile = 128 rows, KV-tile = 64.
// grid 768 = 16b x 12h x 4qt: id%8 = XCD -> b = (id&7)+8*(slot/48) pinned per
// XCD (ploc + K/V L2-local). 768 blocks @ 3 blocks/CU = ALL resident, no tail,
// 6 waves/SIMD for latency hiding (the round-2 bottleneck).
// p = la * exp(s/8 - m): softmax(log la + s/8) without the log; /8 folded
// into the exp via fma.
__global__ __launch_bounds__(512, 6) void attn_mfma(
    const short* __restrict__ Q, const short* __restrict__ K,
    const short* __restrict__ Vt,
    const float* __restrict__ ploc, const float* __restrict__ Wloc,
    const float* __restrict__ bloc, short* __restrict__ out)
{
    __shared__ short Ks[64 * 64];
    __shared__ short Vs[64 * 64];
    __shared__ short bs16[128 * 68];
    __shared__ short Ps[8][16 * 64];

    const int id = blockIdx.x;
    const int xcd = id & 7, slot = id >> 3;       // slot: 0..95
    const int b = xcd + 8 * (slot / 48);
    const int s2 = slot % 48;
    const int h = s2 % 12, qt = s2 / 12;          // qt: 0..3

    const int tid = threadIdx.x;
    const int w = tid >> 6, lane = tid & 63;      // w: 0..7
    const int quad = lane >> 4, l16 = lane & 15;
    const int l8 = lane >> 3, c8 = lane & 7;
    const int q0 = qt * 128;
    const size_t bh = (size_t)b * HH + h;

    float wl[SPDD];
    #pragma unroll
    for (int s = 0; s < SPDD; ++s) wl[s] = Wloc[s * HH + h];
    const float blc = bloc[h];

    const int qr = q0 + w * 16 + l16;
    const bf8_t aq0 = *(const bf8_t*)(Q + (bh * LL + qr) * DHH + quad * 8);
    const bf8_t aq1 = *(const bf8_t*)(Q + (bh * LL + qr) * DHH + quad * 8 + 32);

    f4_t o[4];
    #pragma unroll
    for (int dj = 0; dj < 4; ++dj) o[dj] = (f4_t){0.f, 0.f, 0.f, 0.f};
    float m_row[4], l_row[4];
    #pragma unroll
    for (int r = 0; r < 4; ++r) { m_row[r] = -1e30f; l_row[r] = 0.f; }

    const short* Kg = K  + bh * LL * DHH;
    const short* Vg = Vt + bh * DHH * LL;

    // bias work split: 512 threads cover 128 rows x 64 t, 16 t-elems each
    const int bl = tid >> 2;                // bias row 0..127
    const int ts = (tid & 3) * 16;          // t-offset within tile
    const float* prow = ploc + (size_t)(b * LL + q0 + bl) * LL * SPDD;

    // K/V stage: wave w covers rows w*8..w*8+7; 1 gld16 each per thread.
    // linear LDS dest (base + lane*16B), inverse-swizzled global source.
    const int srow = w * 8 + l8;
    const int ssc  = (c8 ^ l8) * 8;

    for (int t0 = 0; t0 < LL; t0 += 64) {
        __syncthreads();
        gld16(Kg + (size_t)(t0 + srow) * DHH + ssc, Ks + w * 512 + lane * 8);
        gld16(Vg + (size_t)srow * LL + t0 + ssc,    Vs + w * 512 + lane * 8);
        // ---- spatial bias tile (at-use loads; 6 waves/SIMD hide latency) ---
        {
            const float* pp = prow + (size_t)(t0 + ts) * SPDD;
            short o16[16];
            #pragma unroll
            for (int g = 0; g < 4; ++g) {
                f4_t c[5];
                #pragma unroll
                for (int i = 0; i < 5; ++i) c[i] = *(const f4_t*)(pp + g * 20 + i * 4);
                const float* pf = (const float*)c;
                #pragma unroll
                for (int e = 0; e < 4; ++e) {
                    float v = blc;
                    #pragma unroll
                    for (int s = 0; s < SPDD; ++s) v += pf[e * SPDD + s] * wl[s];
                    v = fmaxf(fmaxf(v, 0.f), CLAMP_MINV);
                    o16[g * 4 + e] = f2bf(v);
                }
            }
            #pragma unroll
            for (int i = 0; i < 4; ++i)
                *(short4*)(bs16 + bl * 68 + ts + i * 4) = *(short4*)(o16 + i * 4);
        }
        __syncthreads();

        // ---- S = Q K^T ----
        f4_t sv[4];
        #pragma unroll
        for (int j = 0; j < 4; ++j) {
            const int rB = j * 16 + l16;
            const int x = rB & 7;
            const bf8_t b0 = *(const bf8_t*)(Ks + rB * 64 + ((quad ^ x) * 8));
            const bf8_t b1 = *(const bf8_t*)(Ks + rB * 64 + (((quad + 4) ^ x) * 8));
            f4_t c = (f4_t){0.f, 0.f, 0.f, 0.f};
            c = __builtin_amdgcn_mfma_f32_16x16x32_bf16(aq0, b0, c, 0, 0, 0);
            c = __builtin_amdgcn_mfma_f32_16x16x32_bf16(aq1, b1, c, 0, 0, 0);
            sv[j] = c;
        }

        // ---- online softmax: p = la * exp(s/8 - m), m tracked over s/8 ----
        #pragma unroll
        for (int r = 0; r < 4; ++r) {
            const int lrel = w * 16 + quad * 4 + r;
            float mx = fmaxf(fmaxf(sv[0][r], sv[1][r]), fmaxf(sv[2][r], sv[3][r]));
            mx = fmaxf(mx, __shfl_xor(mx, 1, 16));
            mx = fmaxf(mx, __shfl_xor(mx, 2, 16));
            mx = fmaxf(mx, __shfl_xor(mx, 4, 16));
            mx = fmaxf(mx, __shfl_xor(mx, 8, 16));
            const float mn = fmaxf(m_row[r], mx * 0.125f);
            const float al = __expf(m_row[r] - mn);
            m_row[r] = mn;
            float rs = 0.f;
            #pragma unroll
            for (int j = 0; j < 4; ++j) {
                const float lav = bf2f(bs16[lrel * 68 + j * 16 + l16]);
                const float p = lav * __expf(__builtin_fmaf(sv[j][r], 0.125f, -mn));
                sv[j][r] = p;
                rs += p;
            }
            rs += __shfl_xor(rs, 1, 16);
            rs += __shfl_xor(rs, 2, 16);
            rs += __shfl_xor(rs, 4, 16);
            rs += __shfl_xor(rs, 8, 16);
            l_row[r] = l_row[r] * al + rs;
            #pragma unroll
            for (int dj = 0; dj < 4; ++dj) o[dj][r] *= al;
        }
        // ---- P: C-layout -> swizzled LDS -> A-layout ----
        short* Pw = Ps[w];
        #pragma unroll
        for (int r = 0; r < 4; ++r) {
            const int rp = quad * 4 + r, rp7 = rp & 7;
            #pragma unroll
            for (int j = 0; j < 4; ++j) {
                const int t = j * 16 + l16;
                Pw[rp * 64 + (((t >> 3) ^ rp7) * 8) + (t & 7)] = f2bf(sv[j][r]);
            }
        }
        const int m7 = l16 & 7;
        const bf8_t ap0 = *(const bf8_t*)(Pw + l16 * 64 + ((quad ^ m7) * 8));
        const bf8_t ap1 = *(const bf8_t*)(Pw + l16 * 64 + (((quad + 4) ^ m7) * 8));
        #pragma unroll
        for (int dj = 0; dj < 4; ++dj) {
            const int rB = dj * 16 + l16;
            const int x = rB & 7;
            const bf8_t b0 = *(const bf8_t*)(Vs + rB * 64 + ((quad ^ x) * 8));
            const bf8_t b1 = *(const bf8_t*)(Vs + rB * 64 + (((quad + 4) ^ x) * 8));
            o[dj] = __builtin_amdgcn_mfma_f32_16x16x32_bf16(ap0, b0, o[dj], 0, 0, 0);
            o[dj] = __builtin_amdgcn_mfma_f32_16x16x32_bf16(ap1, b1, o[dj], 0, 0, 0);
        }
    }

    #pragma unroll
    for (int r = 0; r < 4; ++r) {
        const int l = q0 + w * 16 + quad * 4 + r;
        const float inv = 1.f / l_row[r];
        short* op = out + ((size_t)b * LL + l) * DD + h * DHH;
        #pragma unroll
        for (int dj = 0; dj < 4; ++dj)
            op[dj * 16 + l16] = f2bf(o[dj][r] * inv);
    }
}

// ---------------- residual + LayerNorm --------------------------------------
__global__ __launch_bounds__(256) void ln_kernel(
    const float* __restrict__ x, const float* __restrict__ tgt,
    const float* __restrict__ g, const float* __restrict__ bta,
    float* __restrict__ out)
{
    const int row = blockIdx.x;
    const int tid = threadIdx.x;
    __shared__ float red[4];

    const float* xp = x + (size_t)row * DD;
    const float* tp = tgt + (size_t)row * DD;

    float vals[3];
    float s = 0.f;
    #pragma unroll
    for (int i = 0; i < 3; ++i) {
        const float v = xp[tid + i * 256] + tp[tid + i * 256];
        vals[i] = v;
        s += v;
    }
    s = block_sum(s, red, tid);
    const float mu = s * (1.f / 768.f);

    float vs = 0.f;
    #pragma unroll
    for (int i = 0; i < 3; ++i) {
        const float dv = vals[i] - mu;
        vs += dv * dv;
    }
    vs = block_sum(vs, red, tid);
    const float rstd = rsqrtf(vs * (1.f / 768.f) + LN_EPS);

    #pragma unroll
    for (int i = 0; i < 3; ++i) {
        const int cidx = tid + i * 256;
        out[(size_t)row * DD + cidx] = g[cidx] * (vals[i] - mu) * rstd + bta[cidx];
    }
}

// ---------------- launch -----------------------------------------------------
extern "C" void kernel_launch(void* const* d_in, const int* in_sizes, int n_in,
                              void* d_out, int out_size, void* d_ws, size_t ws_size,
                              hipStream_t stream) {
    const float* tgt   = (const float*)d_in[0];
    const float* qpos  = (const float*)d_in[1];
    const float* ploc  = (const float*)d_in[2];
    const float* Wq    = (const float*)d_in[3];
    const float* bq    = (const float*)d_in[4];
    const float* Wk    = (const float*)d_in[5];
    const float* bk    = (const float*)d_in[6];
    const float* Wv    = (const float*)d_in[7];
    const float* bv    = (const float*)d_in[8];
    const float* Wo    = (const float*)d_in[9];
    const float* bo    = (const float*)d_in[10];
    const float* Wloc  = (const float*)d_in[11];
    const float* bloc  = (const float*)d_in[12];
    const float* ln_g  = (const float*)d_in[13];
    const float* ln_b  = (const float*)d_in[14];

    const size_t NQ = (size_t)MM * DD;           // 6291456
    const size_t NW = (size_t)DD * DD;           // 589824

    short* qb   = (short*)d_ws;
    short* kb   = qb  + NQ;
    short* vtb  = kb  + NQ;
    short* aob  = vtb + NQ;
    short* aqk  = aob + NQ;
    short* av   = aqk + NQ;
    float* pbuf = (float*)aqk;                   // alias (aqk,av dead by then)
    short* wqt  = av + NQ;
    short* wkt  = wqt + NW;
    short* wvt  = wkt + NW;
    short* wot  = wvt + NW;

    prep_kernel<<<3648, 256, 0, stream>>>(tgt, qpos, Wq, Wk, Wv, Wo,
                                          aqk, av, wqt, wkt, wvt, wot);

    gemm_qkv<<<dim3(18, 64), 256, 0, stream>>>(aqk, av, wqt, bq, qb,
                                               wkt, bk, kb, wvt, bv, vtb);

    attn_mfma<<<768, 512, 0, stream>>>(qb, kb, vtb, ploc, Wloc, bloc, aob);

    gemm_o<<<dim3(6, 64), 256, 0, stream>>>(aob, wot, bo, pbuf);

    ln_kernel<<<MM, 256, 0, stream>>>(pbuf, tgt, ln_g, ln_b, (float*)d_out);
}

// Round 4
// 406.492 us; speedup vs baseline: 1.1256x; 1.1256x over previous
//
#include <hip/hip_runtime.h>
#include <math.h>

#define BB 16
#define LL 512
#define DD 768
#define HH 12
#define DHH 64
#define SPDD 5
#define MM (BB*LL)   // 8192
#define LN_EPS 1e-5f
#define CLAMP_MINV 1e-6f

typedef __attribute__((ext_vector_type(8))) short bf8_t;
typedef __attribute__((ext_vector_type(4))) float f4_t;

__device__ __forceinline__ short f2bf(float x) {
    unsigned u = __builtin_bit_cast(unsigned, x);
    unsigned r = (u + 0x7FFFu + ((u >> 16) & 1u)) >> 16;
    return (short)r;
}
__device__ __forceinline__ float bf2f(short s) {
    unsigned u = ((unsigned)(unsigned short)s) << 16;
    return __builtin_bit_cast(float, u);
}

__device__ __forceinline__ void gld16(const short* g, short* l) {
    __builtin_amdgcn_global_load_lds(
        (const __attribute__((address_space(1))) unsigned int*)g,
        (__attribute__((address_space(3))) unsigned int*)l,
        16, 0, 0);
}

// ---------------- block reduce (256 threads, wave64) ------------------------
__device__ __forceinline__ float block_sum(float v, float* red, int tid) {
    #pragma unroll
    for (int off = 32; off; off >>= 1) v += __shfl_down(v, off, 64);
    __syncthreads();
    if ((tid & 63) == 0) red[tid >> 6] = v;
    __syncthreads();
    return red[0] + red[1] + red[2] + red[3];
}

// ---------------- fused prep: la-bias + input cast + weight transpose -------
// blocks [0,2048): la[b][h][l][t] = bf16(max(ploc·Wloc+bloc, 1e-6))
// blocks [2048,5120): aqk = bf16(tgt+qpos), av = bf16(tgt)
// blocks [5120,5696): Wt[n][k] = bf16(W[k][n]) for 4 weights
__global__ __launch_bounds__(256) void prep_kernel(
    const float* __restrict__ tgt, const float* __restrict__ qpos,
    const float* __restrict__ ploc, const float* __restrict__ Wloc,
    const float* __restrict__ bloc,
    const float* __restrict__ W0, const float* __restrict__ W1,
    const float* __restrict__ W2, const float* __restrict__ W3,
    short* __restrict__ aqk, short* __restrict__ av, short* __restrict__ la,
    short* __restrict__ O0, short* __restrict__ O1,
    short* __restrict__ O2, short* __restrict__ O3)
{
    __shared__ float T[64][65];
    const int t = blockIdx.x;
    if (t < 2048) {
        // ---- spatial la precompute ----
        const int g   = t * 256 + threadIdx.x;
        const int tch = g & 63;
        const int l   = (g >> 6) & 511;
        const int b   = g >> 15;
        const int t0  = tch * 8;
        float p[40];
        const float* src = ploc + (((size_t)b * LL + l) * LL + t0) * SPDD;
        #pragma unroll
        for (int i = 0; i < 10; ++i)
            *(float4*)(p + i * 4) = *(const float4*)(src + i * 4);
        #pragma unroll
        for (int h = 0; h < HH; ++h) {
            float wl[SPDD];
            #pragma unroll
            for (int s = 0; s < SPDD; ++s) wl[s] = Wloc[s * HH + h];
            const float bl = bloc[h];
            short o[8];
            #pragma unroll
            for (int i = 0; i < 8; ++i) {
                float v = bl;
                #pragma unroll
                for (int s = 0; s < SPDD; ++s) v += p[i * SPDD + s] * wl[s];
                // relu then clip(1e-6) == max(v, 1e-6)
                o[i] = f2bf(fmaxf(v, CLAMP_MINV));
            }
            *(bf8_t*)(la + (((size_t)(b * HH + h) * LL + l) * LL + t0)) = *(bf8_t*)o;
        }
    } else if (t < 5120) {
        // ---- input cast ----
        const int cb = t - 2048;
        const size_t base = ((size_t)cb * 256 + threadIdx.x) * 8;
        const float4 t0 = *(const float4*)(tgt + base);
        const float4 t1 = *(const float4*)(tgt + base + 4);
        const float4 p0 = *(const float4*)(qpos + base);
        const float4 p1 = *(const float4*)(qpos + base + 4);
        short v[8], q[8];
        v[0] = f2bf(t0.x); v[1] = f2bf(t0.y); v[2] = f2bf(t0.z); v[3] = f2bf(t0.w);
        v[4] = f2bf(t1.x); v[5] = f2bf(t1.y); v[6] = f2bf(t1.z); v[7] = f2bf(t1.w);
        q[0] = f2bf(t0.x + p0.x); q[1] = f2bf(t0.y + p0.y);
        q[2] = f2bf(t0.z + p0.z); q[3] = f2bf(t0.w + p0.w);
        q[4] = f2bf(t1.x + p1.x); q[5] = f2bf(t1.y + p1.y);
        q[6] = f2bf(t1.z + p1.z); q[7] = f2bf(t1.w + p1.w);
        *(bf8_t*)(av + base)  = *(bf8_t*)v;
        *(bf8_t*)(aqk + base) = *(bf8_t*)q;
    } else {
        // ---- weight transpose + cast ----
        const int wt = t - 5120;                // 0..575
        const int wi = wt / 144;
        const int rem = wt % 144;
        const float* W; short* O;
        switch (wi) {
            case 0: W = W0; O = O0; break;
            case 1: W = W1; O = O1; break;
            case 2: W = W2; O = O2; break;
            default: W = W3; O = O3; break;
        }
        const int n0 = (rem % 12) * 64, k0 = (rem / 12) * 64;
        const int tid = threadIdx.x;
        {
            const int kk = tid >> 4, nv = (tid & 15) * 4;
            #pragma unroll
            for (int i = 0; i < 4; ++i) {
                const int k = kk + i * 16;
                const float4 v = *(const float4*)(W + (size_t)(k0 + k) * DD + n0 + nv);
                T[k][nv + 0] = v.x; T[k][nv + 1] = v.y;
                T[k][nv + 2] = v.z; T[k][nv + 3] = v.w;
            }
        }
        __syncthreads();
        {
            const int n = tid >> 2, kc = (tid & 3) * 16;
            short tmp[16];
            #pragma unroll
            for (int i = 0; i < 16; ++i) tmp[i] = f2bf(T[kc + i][n]);
            short* dst = O + (size_t)(n0 + n) * DD + k0 + kc;
            *(bf8_t*)dst       = *(bf8_t*)tmp;
            *(bf8_t*)(dst + 8) = *(bf8_t*)(tmp + 8);
        }
    }
}

// ---------------- fused Q/K/V bf16 MFMA GEMM (XCD-swizzled) -----------------
// Epilogue stages the C-tile through LDS (reusing As) so ALL global stores
// are coalesced 16B vectors (the old path did 64 scalar 2B stores/thread;
// for V^T the 64 lanes were 1KB apart = 64 L2 transactions per instruction).
__global__ __launch_bounds__(256) void gemm_qkv(
    const short* __restrict__ Aqk, const short* __restrict__ Av,
    const short* __restrict__ Wq, const float* __restrict__ bq, short* __restrict__ oq,
    const short* __restrict__ Wk, const float* __restrict__ bk, short* __restrict__ ok,
    const short* __restrict__ Wv, const float* __restrict__ bv, short* __restrict__ ov)
{
    __shared__ short As[128 * 64];
    __shared__ short Bs[128 * 64];
    // XCD remap: id%8 = XCD (round-robin); give each XCD 8 contiguous m-blocks
    const int id = blockIdx.y * 18 + blockIdx.x;
    const int xcd = id & 7, j = id >> 3;          // j: 0..143
    const int by = xcd * 8 + j / 18;
    const int gx = j % 18;
    const int seg = gx / 6;
    const int bx = gx % 6;
    const short* A  = (seg == 2) ? Av : Aqk;
    const short* Wt = (seg == 0) ? Wq : (seg == 1) ? Wk : Wv;
    const float* bias = (seg == 0) ? bq : (seg == 1) ? bk : bv;
    short* out = (seg == 0) ? oq : (seg == 1) ? ok : ov;

    const int n0 = bx * 128, m0 = by * 128;
    const int tid = threadIdx.x;
    const int w = tid >> 6, lane = tid & 63;
    const int quad = lane >> 4, l16 = lane & 15;
    const int wm = w & 1, wn = w >> 1;
    const int sr = w * 8 + (lane >> 3);
    const int sp = lane & 7;

    f4_t acc[4][4];
    #pragma unroll
    for (int i = 0; i < 4; ++i)
        #pragma unroll
        for (int jj = 0; jj < 4; ++jj) acc[i][jj] = (f4_t){0.f, 0.f, 0.f, 0.f};

    for (int k0 = 0; k0 < DD; k0 += 64) {
        __syncthreads();
        #pragma unroll
        for (int ra = 0; ra < 4; ++ra) {
            const int r = sr + ra * 32;
            const int c = sp ^ (r & 7);
            const int ldso = ra * 2048 + w * 512 + lane * 8;
            gld16(A  + (size_t)(m0 + r) * DD + k0 + c * 8, As + ldso);
            gld16(Wt + (size_t)(n0 + r) * DD + k0 + c * 8, Bs + ldso);
        }
        __syncthreads();
        #pragma unroll
        for (int s = 0; s < 2; ++s) {
            bf8_t a[4], b[4];
            #pragma unroll
            for (int i = 0; i < 4; ++i) {
                const int rA = wm * 64 + i * 16 + l16;
                const int pA = (s * 4 + quad) ^ (rA & 7);
                a[i] = *(const bf8_t*)(As + rA * 64 + pA * 8);
                const int rB = wn * 64 + i * 16 + l16;
                const int pB = (s * 4 + quad) ^ (rB & 7);
                b[i] = *(const bf8_t*)(Bs + rB * 64 + pB * 8);
            }
            #pragma unroll
            for (int i = 0; i < 4; ++i)
                #pragma unroll
                for (int jj = 0; jj < 4; ++jj)
                    acc[i][jj] = __builtin_amdgcn_mfma_f32_16x16x32_bf16(a[i], b[jj], acc[i][jj], 0, 0, 0);
        }
    }

    float bvv[4];
    #pragma unroll
    for (int jj = 0; jj < 4; ++jj) bvv[jj] = bias[n0 + wn * 64 + jj * 16 + l16];

    const int b_ = m0 >> 9;                 // batch (128-row tile never spans)
    const int ml = m0 & 511;                // l-offset of this tile

    // two phases: n-half ph (cols ph*64..ph*64+63) staged in As[128][64]
    #pragma unroll
    for (int ph = 0; ph < 2; ++ph) {
        __syncthreads();
        if (wn == ph) {
            #pragma unroll
            for (int i = 0; i < 4; ++i)
                #pragma unroll
                for (int jj = 0; jj < 4; ++jj) {
                    const int col = jj * 16 + l16;
                    #pragma unroll
                    for (int r = 0; r < 4; ++r) {
                        const int mr = wm * 64 + i * 16 + quad * 4 + r;
                        As[mr * 64 + (((col >> 3) ^ (mr & 7)) * 8) + (col & 7)]
                            = f2bf(acc[i][jj][r] + bvv[jj]);
                    }
                }
        }
        __syncthreads();
        const int h = (n0 >> 6) + ph;
        if (seg < 2) {
            // out[(b*H+h)*L + l][d]: 128B contiguous per row
            const int row = tid >> 1, part = tid & 1;
            short tmp[32];
            #pragma unroll
            for (int g = 0; g < 4; ++g) {
                const int colg = part * 4 + g;
                *(bf8_t*)(tmp + g * 8) =
                    *(const bf8_t*)(As + row * 64 + ((colg ^ (row & 7)) * 8));
            }
            short* dst = out + (((size_t)(b_ * HH + h)) * LL + ml + row) * DHH + part * 32;
            #pragma unroll
            for (int g = 0; g < 4; ++g)
                *(bf8_t*)(dst + g * 8) = *(bf8_t*)(tmp + g * 8);
        } else {
            // V^T: out[(b*H+h)*DH + d][l]: contiguous along l
            const int col = tid >> 2, q4 = tid & 3;   // d-local, l-quarter
            short tmp[32];
            #pragma unroll
            for (int k = 0; k < 32; ++k) {
                const int row = q4 * 32 + k;
                tmp[k] = As[row * 64 + (((col >> 3) ^ (row & 7)) * 8) + (col & 7)];
            }
            short* dst = out + (((size_t)(b_ * HH + h)) * DHH + col) * LL + ml + q4 * 32;
            #pragma unroll
            for (int g = 0; g < 4; ++g)
                *(bf8_t*)(dst + g * 8) = *(bf8_t*)(tmp + g * 8);
        }
    }
}

// ---------------- O-projection GEMM (XCD-swizzled, fp32 out) ----------------
__global__ __launch_bounds__(256) void gemm_o(
    const short* __restrict__ A, const short* __restrict__ Wt,
    const float* __restrict__ bias, float* __restrict__ out)
{
    __shared__ short As[128 * 64];
    __shared__ short Bs[128 * 64];
    const int id = blockIdx.y * 6 + blockIdx.x;
    const int xcd = id & 7, j = id >> 3;          // j: 0..47
    const int by = xcd * 8 + j / 6;
    const int bx = j % 6;
    const int n0 = bx * 128, m0 = by * 128;
    const int tid = threadIdx.x;
    const int w = tid >> 6, lane = tid & 63;
    const int quad = lane >> 4, l16 = lane & 15;
    const int wm = w & 1, wn = w >> 1;
    const int sr = w * 8 + (lane >> 3);
    const int sp = lane & 7;

    f4_t acc[4][4];
    #pragma unroll
    for (int i = 0; i < 4; ++i)
        #pragma unroll
        for (int jj = 0; jj < 4; ++jj) acc[i][jj] = (f4_t){0.f, 0.f, 0.f, 0.f};

    for (int k0 = 0; k0 < DD; k0 += 64) {
        __syncthreads();
        #pragma unroll
        for (int ra = 0; ra < 4; ++ra) {
            const int r = sr + ra * 32;
            const int c = sp ^ (r & 7);
            const int ldso = ra * 2048 + w * 512 + lane * 8;
            gld16(A  + (size_t)(m0 + r) * DD + k0 + c * 8, As + ldso);
            gld16(Wt + (size_t)(n0 + r) * DD + k0 + c * 8, Bs + ldso);
        }
        __syncthreads();
        #pragma unroll
        for (int s = 0; s < 2; ++s) {
            bf8_t a[4], b[4];
            #pragma unroll
            for (int i = 0; i < 4; ++i) {
                const int rA = wm * 64 + i * 16 + l16;
                const int pA = (s * 4 + quad) ^ (rA & 7);
                a[i] = *(const bf8_t*)(As + rA * 64 + pA * 8);
                const int rB = wn * 64 + i * 16 + l16;
                const int pB = (s * 4 + quad) ^ (rB & 7);
                b[i] = *(const bf8_t*)(Bs + rB * 64 + pB * 8);
            }
            #pragma unroll
            for (int i = 0; i < 4; ++i)
                #pragma unroll
                for (int jj = 0; jj < 4; ++jj)
                    acc[i][jj] = __builtin_amdgcn_mfma_f32_16x16x32_bf16(a[i], b[jj], acc[i][jj], 0, 0, 0);
        }
    }

    float bvv[4];
    #pragma unroll
    for (int jj = 0; jj < 4; ++jj) bvv[jj] = bias[n0 + wn * 64 + jj * 16 + l16];
    #pragma unroll
    for (int i = 0; i < 4; ++i)
        #pragma unroll
        for (int jj = 0; jj < 4; ++jj) {
            const int n = n0 + wn * 64 + jj * 16 + l16;
            #pragma unroll
            for (int r = 0; r < 4; ++r) {
                const int m = m0 + wm * 64 + i * 16 + quad * 4 + r;
                out[(size_t)m * DD + n] = acc[i][jj][r] + bvv[jj];
            }
        }
}

// ---------------- flash-style MFMA attention --------------------------------
// grid (192, 8): x = h + 12*b, y = qt  (qt slowest -> same-(b,h) blocks on one XCD)
// p = la * exp(s/8 - m): softmax(log la + s/8) without the log; /8 folded
// into the exp via fma.
__global__ __launch_bounds__(256) void attn_mfma(
    const short* __restrict__ Q, const short* __restrict__ K,
    const short* __restrict__ Vt, const short* __restrict__ LA,
    short* __restrict__ out)
{
    __shared__ short Ks[64 * 64];
    __shared__ short Vs[64 * 64];
    __shared__ short bs16[64 * 68];
    __shared__ short Ps[4][16 * 64];

    const int h = blockIdx.x % 12, b = blockIdx.x / 12;
    const int qt = blockIdx.y;
    const int tid = threadIdx.x;
    const int w = tid >> 6, lane = tid & 63;
    const int quad = lane >> 4, l16 = lane & 15;
    const int q0 = qt * 64;
    const size_t bh = (size_t)b * HH + h;

    const int qr = q0 + w * 16 + l16;
    const bf8_t aq0 = *(const bf8_t*)(Q + (bh * LL + qr) * DHH + quad * 8);
    const bf8_t aq1 = *(const bf8_t*)(Q + (bh * LL + qr) * DHH + quad * 8 + 32);

    f4_t o[4];
    #pragma unroll
    for (int dj = 0; dj < 4; ++dj) o[dj] = (f4_t){0.f, 0.f, 0.f, 0.f};
    float m_row[4], l_row[4];
    #pragma unroll
    for (int r = 0; r < 4; ++r) { m_row[r] = -1e30f; l_row[r] = 0.f; }

    const short* Kg = K  + bh * LL * DHH;
    const short* Vg = Vt + bh * DHH * LL;
    const short* Bg = LA + (bh * LL + q0) * LL;

    const int srow = tid >> 2;
    const int cb   = (tid & 3) * 2;
    const int sw   = srow & 7;

    for (int t0 = 0; t0 < LL; t0 += 64) {
        __syncthreads();
        {
            const short* src = Kg + (size_t)(t0 + srow) * DHH + cb * 8;
            *(bf8_t*)(Ks + srow * 64 + ((cb ^ sw) * 8))       = *(const bf8_t*)(src);
            *(bf8_t*)(Ks + srow * 64 + (((cb + 1) ^ sw) * 8)) = *(const bf8_t*)(src + 8);
        }
        {
            const short* src = Vg + (size_t)srow * LL + t0 + cb * 8;
            *(bf8_t*)(Vs + srow * 64 + ((cb ^ sw) * 8))       = *(const bf8_t*)(src);
            *(bf8_t*)(Vs + srow * 64 + (((cb + 1) ^ sw) * 8)) = *(const bf8_t*)(src + 8);
        }
        {
            const int l = tid >> 2, ts = (tid & 3) * 16;
            const short* src = Bg + (size_t)l * LL + t0 + ts;
            #pragma unroll
            for (int i = 0; i < 4; ++i)
                *(short4*)(bs16 + l * 68 + ts + i * 4) = *(const short4*)(src + i * 4);
        }
        __syncthreads();

        // ---- S = Q K^T ----
        f4_t sv[4];
        #pragma unroll
        for (int j = 0; j < 4; ++j) {
            const int rB = j * 16 + l16;
            const int x = rB & 7;
            const bf8_t b0 = *(const bf8_t*)(Ks + rB * 64 + ((quad ^ x) * 8));
            const bf8_t b1 = *(const bf8_t*)(Ks + rB * 64 + (((quad + 4) ^ x) * 8));
            f4_t c = (f4_t){0.f, 0.f, 0.f, 0.f};
            c = __builtin_amdgcn_mfma_f32_16x16x32_bf16(aq0, b0, c, 0, 0, 0);
            c = __builtin_amdgcn_mfma_f32_16x16x32_bf16(aq1, b1, c, 0, 0, 0);
            sv[j] = c;
        }

        // ---- online softmax: p = la * exp(s/8 - m), m tracked over s/8 ----
        #pragma unroll
        for (int r = 0; r < 4; ++r) {
            const int lrel = w * 16 + quad * 4 + r;
            float mx = fmaxf(fmaxf(sv[0][r], sv[1][r]), fmaxf(sv[2][r], sv[3][r]));
            mx = fmaxf(mx, __shfl_xor(mx, 1, 16));
            mx = fmaxf(mx, __shfl_xor(mx, 2, 16));
            mx = fmaxf(mx, __shfl_xor(mx, 4, 16));
            mx = fmaxf(mx, __shfl_xor(mx, 8, 16));
            const float mn = fmaxf(m_row[r], mx * 0.125f);
            const float al = __expf(m_row[r] - mn);
            m_row[r] = mn;
            float rs = 0.f;
            #pragma unroll
            for (int j = 0; j < 4; ++j) {
                const float lav = bf2f(bs16[lrel * 68 + j * 16 + l16]);
                const float p = lav * __expf(__builtin_fmaf(sv[j][r], 0.125f, -mn));
                sv[j][r] = p;
                rs += p;
            }
            rs += __shfl_xor(rs, 1, 16);
            rs += __shfl_xor(rs, 2, 16);
            rs += __shfl_xor(rs, 4, 16);
            rs += __shfl_xor(rs, 8, 16);
            l_row[r] = l_row[r] * al + rs;
            #pragma unroll
            for (int dj = 0; dj < 4; ++dj) o[dj][r] *= al;
        }
        // ---- P: C-layout -> swizzled LDS -> A-layout ----
        short* Pw = Ps[w];
        #pragma unroll
        for (int r = 0; r < 4; ++r) {
            const int rp = quad * 4 + r, rp7 = rp & 7;
            #pragma unroll
            for (int j = 0; j < 4; ++j) {
                const int t = j * 16 + l16;
                Pw[rp * 64 + (((t >> 3) ^ rp7) * 8) + (t & 7)] = f2bf(sv[j][r]);
            }
        }
        const int m7 = l16 & 7;
        const bf8_t ap0 = *(const bf8_t*)(Pw + l16 * 64 + ((quad ^ m7) * 8));
        const bf8_t ap1 = *(const bf8_t*)(Pw + l16 * 64 + (((quad + 4) ^ m7) * 8));
        #pragma unroll
        for (int dj = 0; dj < 4; ++dj) {
            const int rB = dj * 16 + l16;
            const int x = rB & 7;
            const bf8_t b0 = *(const bf8_t*)(Vs + rB * 64 + ((quad ^ x) * 8));
            const bf8_t b1 = *(const bf8_t*)(Vs + rB * 64 + (((quad + 4) ^ x) * 8));
            o[dj] = __builtin_amdgcn_mfma_f32_16x16x32_bf16(ap0, b0, o[dj], 0, 0, 0);
            o[dj] = __builtin_amdgcn_mfma_f32_16x16x32_bf16(ap1, b1, o[dj], 0, 0, 0);
        }
    }

    #pragma unroll
    for (int r = 0; r < 4; ++r) {
        const int l = q0 + w * 16 + quad * 4 + r;
        const float inv = 1.f / l_row[r];
        short* op = out + ((size_t)b * LL + l) * DD + h * DHH;
        #pragma unroll
        for (int dj = 0; dj < 4; ++dj)
            op[dj * 16 + l16] = f2bf(o[dj][r] * inv);
    }
}

// ---------------- residual + LayerNorm --------------------------------------
__global__ __launch_bounds__(256) void ln_kernel(
    const float* __restrict__ x, const float* __restrict__ tgt,
    const float* __restrict__ g, const float* __restrict__ bta,
    float* __restrict__ out)
{
    const int row = blockIdx.x;
    const int tid = threadIdx.x;
    __shared__ float red[4];

    const float* xp = x + (size_t)row * DD;
    const float* tp = tgt + (size_t)row * DD;

    float vals[3];
    float s = 0.f;
    #pragma unroll
    for (int i = 0; i < 3; ++i) {
        const float v = xp[tid + i * 256] + tp[tid + i * 256];
        vals[i] = v;
        s += v;
    }
    s = block_sum(s, red, tid);
    const float mu = s * (1.f / 768.f);

    float vs = 0.f;
    #pragma unroll
    for (int i = 0; i < 3; ++i) {
        const float dv = vals[i] - mu;
        vs += dv * dv;
    }
    vs = block_sum(vs, red, tid);
    const float rstd = rsqrtf(vs * (1.f / 768.f) + LN_EPS);

    #pragma unroll
    for (int i = 0; i < 3; ++i) {
        const int cidx = tid + i * 256;
        out[(size_t)row * DD + cidx] = g[cidx] * (vals[i] - mu) * rstd + bta[cidx];
    }
}

// ---------------- launch -----------------------------------------------------
extern "C" void kernel_launch(void* const* d_in, const int* in_sizes, int n_in,
                              void* d_out, int out_size, void* d_ws, size_t ws_size,
                              hipStream_t stream) {
    const float* tgt   = (const float*)d_in[0];
    const float* qpos  = (const float*)d_in[1];
    const float* ploc  = (const float*)d_in[2];
    const float* Wq    = (const float*)d_in[3];
    const float* bq    = (const float*)d_in[4];
    const float* Wk    = (const float*)d_in[5];
    const float* bk    = (const float*)d_in[6];
    const float* Wv    = (const float*)d_in[7];
    const float* bv    = (const float*)d_in[8];
    const float* Wo    = (const float*)d_in[9];
    const float* bo    = (const float*)d_in[10];
    const float* Wloc  = (const float*)d_in[11];
    const float* bloc  = (const float*)d_in[12];
    const float* ln_g  = (const float*)d_in[13];
    const float* ln_b  = (const float*)d_in[14];

    const size_t NQ = (size_t)MM * DD;           // 6291456
    const size_t NW = (size_t)DD * DD;           // 589824

    short* qb   = (short*)d_ws;
    short* kb   = qb  + NQ;
    short* vtb  = kb  + NQ;
    short* aob  = vtb + NQ;
    short* aqk  = aob + NQ;
    short* av   = aqk + NQ;
    float* pbuf = (float*)aqk;                   // alias (aqk,av dead by then)
    short* wqt  = av + NQ;
    short* wkt  = wqt + NW;
    short* wvt  = wkt + NW;
    short* wot  = wvt + NW;
    short* lab  = wot + NW;

    prep_kernel<<<5696, 256, 0, stream>>>(tgt, qpos, ploc, Wloc, bloc,
                                          Wq, Wk, Wv, Wo,
                                          aqk, av, lab, wqt, wkt, wvt, wot);

    gemm_qkv<<<dim3(18, 64), 256, 0, stream>>>(aqk, av, wqt, bq, qb,
                                               wkt, bk, kb, wvt, bv, vtb);

    attn_mfma<<<dim3(192, 8), 256, 0, stream>>>(qb, kb, vtb, lab, aob);

    gemm_o<<<dim3(6, 64), 256, 0, stream>>>(aob, wot, bo, pbuf);

    ln_kernel<<<MM, 256, 0, stream>>>(pbuf, tgt, ln_g, ln_b, (float*)d_out);
}

// Round 5
// 346.555 us; speedup vs baseline: 1.3202x; 1.1730x over previous
//
#include <hip/hip_runtime.h>
#include <math.h>

#define BB 16
#define LL 512
#define DD 768
#define HH 12
#define DHH 64
#define SPDD 5
#define MM (BB*LL)   // 8192
#define LN_EPS 1e-5f
#define CLAMP_MINV 1e-6f

typedef __attribute__((ext_vector_type(8))) short bf8_t;
typedef __attribute__((ext_vector_type(4))) float f4_t;

__device__ __forceinline__ short f2bf(float x) {
    unsigned u = __builtin_bit_cast(unsigned, x);
    unsigned r = (u + 0x7FFFu + ((u >> 16) & 1u)) >> 16;
    return (short)r;
}
__device__ __forceinline__ float bf2f(short s) {
    unsigned u = ((unsigned)(unsigned short)s) << 16;
    return __builtin_bit_cast(float, u);
}

__device__ __forceinline__ void gld16(const short* g, short* l) {
    __builtin_amdgcn_global_load_lds(
        (const __attribute__((address_space(1))) unsigned int*)g,
        (__attribute__((address_space(3))) unsigned int*)l,
        16, 0, 0);
}

// ---------------- block reduce (256 threads, wave64) ------------------------
__device__ __forceinline__ float block_sum(float v, float* red, int tid) {
    #pragma unroll
    for (int off = 32; off; off >>= 1) v += __shfl_down(v, off, 64);
    __syncthreads();
    if ((tid & 63) == 0) red[tid >> 6] = v;
    __syncthreads();
    return red[0] + red[1] + red[2] + red[3];
}

// ---------------- prep: input cast + weight transpose -----------------------
// blocks [0,3072): aqk = bf16(tgt+qpos), av = bf16(tgt)
// blocks [3072,3648): Wt[n][k] = bf16(W[k][n]) for 4 weights
__global__ __launch_bounds__(256) void prep_kernel(
    const float* __restrict__ tgt, const float* __restrict__ qpos,
    const float* __restrict__ W0, const float* __restrict__ W1,
    const float* __restrict__ W2, const float* __restrict__ W3,
    short* __restrict__ aqk, short* __restrict__ av,
    short* __restrict__ O0, short* __restrict__ O1,
    short* __restrict__ O2, short* __restrict__ O3)
{
    __shared__ float T[64][65];
    const int t = blockIdx.x;
    if (t < 3072) {
        // ---- input cast ----
        const size_t base = ((size_t)t * 256 + threadIdx.x) * 8;
        const float4 t0 = *(const float4*)(tgt + base);
        const float4 t1 = *(const float4*)(tgt + base + 4);
        const float4 p0 = *(const float4*)(qpos + base);
        const float4 p1 = *(const float4*)(qpos + base + 4);
        short v[8], q[8];
        v[0] = f2bf(t0.x); v[1] = f2bf(t0.y); v[2] = f2bf(t0.z); v[3] = f2bf(t0.w);
        v[4] = f2bf(t1.x); v[5] = f2bf(t1.y); v[6] = f2bf(t1.z); v[7] = f2bf(t1.w);
        q[0] = f2bf(t0.x + p0.x); q[1] = f2bf(t0.y + p0.y);
        q[2] = f2bf(t0.z + p0.z); q[3] = f2bf(t0.w + p0.w);
        q[4] = f2bf(t1.x + p1.x); q[5] = f2bf(t1.y + p1.y);
        q[6] = f2bf(t1.z + p1.z); q[7] = f2bf(t1.w + p1.w);
        *(bf8_t*)(av + base)  = *(bf8_t*)v;
        *(bf8_t*)(aqk + base) = *(bf8_t*)q;
    } else {
        // ---- weight transpose + cast ----
        const int wt = t - 3072;                // 0..575
        const int wi = wt / 144;
        const int rem = wt % 144;
        const float* W; short* O;
        switch (wi) {
            case 0: W = W0; O = O0; break;
            case 1: W = W1; O = O1; break;
            case 2: W = W2; O = O2; break;
            default: W = W3; O = O3; break;
        }
        const int n0 = (rem % 12) * 64, k0 = (rem / 12) * 64;
        const int tid = threadIdx.x;
        {
            const int kk = tid >> 4, nv = (tid & 15) * 4;
            #pragma unroll
            for (int i = 0; i < 4; ++i) {
                const int k = kk + i * 16;
                const float4 v = *(const float4*)(W + (size_t)(k0 + k) * DD + n0 + nv);
                T[k][nv + 0] = v.x; T[k][nv + 1] = v.y;
                T[k][nv + 2] = v.z; T[k][nv + 3] = v.w;
            }
        }
        __syncthreads();
        {
            const int n = tid >> 2, kc = (tid & 3) * 16;
            short tmp[16];
            #pragma unroll
            for (int i = 0; i < 16; ++i) tmp[i] = f2bf(T[kc + i][n]);
            short* dst = O + (size_t)(n0 + n) * DD + k0 + kc;
            *(bf8_t*)dst       = *(bf8_t*)tmp;
            *(bf8_t*)(dst + 8) = *(bf8_t*)(tmp + 8);
        }
    }
}

// ---------------- merged: Q/K/V MFMA GEMM + la-bias precompute --------------
// blocks [0,1152): the XCD-swizzled Q/K/V GEMM (r0 direct-store epilogue).
//   1152 < 1280 residency slots -> every GEMM block resident from t=0.
// blocks [1152,3200): la[b][h][l][t] = bf16(max(ploc·Wloc+bloc, 1e-6)).
//   Independent memory-streaming work that fills the issue slots the
//   latency-bound GEMM leaves idle (MfmaUtil 12%, VALUBusy 18%).
__global__ __launch_bounds__(256) void qkv_la(
    const short* __restrict__ Aqk, const short* __restrict__ Av,
    const short* __restrict__ Wq, const float* __restrict__ bq, short* __restrict__ oq,
    const short* __restrict__ Wk, const float* __restrict__ bk, short* __restrict__ ok,
    const short* __restrict__ Wv, const float* __restrict__ bv, short* __restrict__ ov,
    const float* __restrict__ ploc, const float* __restrict__ Wloc,
    const float* __restrict__ bloc, short* __restrict__ la)
{
    __shared__ short As[128 * 64];
    __shared__ short Bs[128 * 64];
    const int id = blockIdx.x;

    if (id >= 1152) {
        // ---- spatial la precompute ----
        const int g   = (id - 1152) * 256 + threadIdx.x;
        const int tch = g & 63;
        const int l   = (g >> 6) & 511;
        const int b   = g >> 15;
        const int t0  = tch * 8;
        float p[40];
        const float* src = ploc + (((size_t)b * LL + l) * LL + t0) * SPDD;
        #pragma unroll
        for (int i = 0; i < 10; ++i)
            *(float4*)(p + i * 4) = *(const float4*)(src + i * 4);
        #pragma unroll
        for (int h = 0; h < HH; ++h) {
            float wl[SPDD];
            #pragma unroll
            for (int s = 0; s < SPDD; ++s) wl[s] = Wloc[s * HH + h];
            const float bl = bloc[h];
            short o[8];
            #pragma unroll
            for (int i = 0; i < 8; ++i) {
                float v = bl;
                #pragma unroll
                for (int s = 0; s < SPDD; ++s) v += p[i * SPDD + s] * wl[s];
                // relu then clip(1e-6) == max(v, 1e-6)
                o[i] = f2bf(fmaxf(v, CLAMP_MINV));
            }
            *(bf8_t*)(la + (((size_t)(b * HH + h) * LL + l) * LL + t0)) = *(bf8_t*)o;
        }
        return;
    }

    // ---- GEMM path (ids 0..1151; XCD remap identical to r0) ----
    const int xcd = id & 7, j = id >> 3;          // j: 0..143
    const int by = xcd * 8 + j / 18;
    const int gx = j % 18;
    const int seg = gx / 6;
    const int bx = gx % 6;
    const short* A  = (seg == 2) ? Av : Aqk;
    const short* Wt = (seg == 0) ? Wq : (seg == 1) ? Wk : Wv;
    const float* bias = (seg == 0) ? bq : (seg == 1) ? bk : bv;
    short* out = (seg == 0) ? oq : (seg == 1) ? ok : ov;

    const int n0 = bx * 128, m0 = by * 128;
    const int tid = threadIdx.x;
    const int w = tid >> 6, lane = tid & 63;
    const int quad = lane >> 4, l16 = lane & 15;
    const int wm = w & 1, wn = w >> 1;
    const int sr = w * 8 + (lane >> 3);
    const int sp = lane & 7;

    f4_t acc[4][4];
    #pragma unroll
    for (int i = 0; i < 4; ++i)
        #pragma unroll
        for (int jj = 0; jj < 4; ++jj) acc[i][jj] = (f4_t){0.f, 0.f, 0.f, 0.f};

    for (int k0 = 0; k0 < DD; k0 += 64) {
        __syncthreads();
        #pragma unroll
        for (int ra = 0; ra < 4; ++ra) {
            const int r = sr + ra * 32;
            const int c = sp ^ (r & 7);
            const int ldso = ra * 2048 + w * 512 + lane * 8;
            gld16(A  + (size_t)(m0 + r) * DD + k0 + c * 8, As + ldso);
            gld16(Wt + (size_t)(n0 + r) * DD + k0 + c * 8, Bs + ldso);
        }
        __syncthreads();
        #pragma unroll
        for (int s = 0; s < 2; ++s) {
            bf8_t a[4], b[4];
            #pragma unroll
            for (int i = 0; i < 4; ++i) {
                const int rA = wm * 64 + i * 16 + l16;
                const int pA = (s * 4 + quad) ^ (rA & 7);
                a[i] = *(const bf8_t*)(As + rA * 64 + pA * 8);
                const int rB = wn * 64 + i * 16 + l16;
                const int pB = (s * 4 + quad) ^ (rB & 7);
                b[i] = *(const bf8_t*)(Bs + rB * 64 + pB * 8);
            }
            #pragma unroll
            for (int i = 0; i < 4; ++i)
                #pragma unroll
                for (int jj = 0; jj < 4; ++jj)
                    acc[i][jj] = __builtin_amdgcn_mfma_f32_16x16x32_bf16(a[i], b[jj], acc[i][jj], 0, 0, 0);
        }
    }

    float bvv[4];
    #pragma unroll
    for (int jj = 0; jj < 4; ++jj) bvv[jj] = bias[n0 + wn * 64 + jj * 16 + l16];
    #pragma unroll
    for (int i = 0; i < 4; ++i) {
        #pragma unroll
        for (int jj = 0; jj < 4; ++jj) {
            const int n = n0 + wn * 64 + jj * 16 + l16;
            #pragma unroll
            for (int r = 0; r < 4; ++r) {
                const int m = m0 + wm * 64 + i * 16 + quad * 4 + r;
                const float val = acc[i][jj][r] + bvv[jj];
                const int b_ = m >> 9, l = m & 511;
                const int h = n >> 6, d = n & 63;
                if (seg < 2)
                    out[(((size_t)(b_ * HH + h)) * LL + l) * DHH + d] = f2bf(val);
                else
                    out[(((size_t)(b_ * HH + h)) * DHH + d) * LL + l] = f2bf(val);
            }
        }
    }
}

// ---------------- O-projection GEMM (XCD-swizzled, fp32 out) ----------------
__global__ __launch_bounds__(256) void gemm_o(
    const short* __restrict__ A, const short* __restrict__ Wt,
    const float* __restrict__ bias, float* __restrict__ out)
{
    __shared__ short As[128 * 64];
    __shared__ short Bs[128 * 64];
    const int id = blockIdx.y * 6 + blockIdx.x;
    const int xcd = id & 7, j = id >> 3;          // j: 0..47
    const int by = xcd * 8 + j / 6;
    const int bx = j % 6;
    const int n0 = bx * 128, m0 = by * 128;
    const int tid = threadIdx.x;
    const int w = tid >> 6, lane = tid & 63;
    const int quad = lane >> 4, l16 = lane & 15;
    const int wm = w & 1, wn = w >> 1;
    const int sr = w * 8 + (lane >> 3);
    const int sp = lane & 7;

    f4_t acc[4][4];
    #pragma unroll
    for (int i = 0; i < 4; ++i)
        #pragma unroll
        for (int jj = 0; jj < 4; ++jj) acc[i][jj] = (f4_t){0.f, 0.f, 0.f, 0.f};

    for (int k0 = 0; k0 < DD; k0 += 64) {
        __syncthreads();
        #pragma unroll
        for (int ra = 0; ra < 4; ++ra) {
            const int r = sr + ra * 32;
            const int c = sp ^ (r & 7);
            const int ldso = ra * 2048 + w * 512 + lane * 8;
            gld16(A  + (size_t)(m0 + r) * DD + k0 + c * 8, As + ldso);
            gld16(Wt + (size_t)(n0 + r) * DD + k0 + c * 8, Bs + ldso);
        }
        __syncthreads();
        #pragma unroll
        for (int s = 0; s < 2; ++s) {
            bf8_t a[4], b[4];
            #pragma unroll
            for (int i = 0; i < 4; ++i) {
                const int rA = wm * 64 + i * 16 + l16;
                const int pA = (s * 4 + quad) ^ (rA & 7);
                a[i] = *(const bf8_t*)(As + rA * 64 + pA * 8);
                const int rB = wn * 64 + i * 16 + l16;
                const int pB = (s * 4 + quad) ^ (rB & 7);
                b[i] = *(const bf8_t*)(Bs + rB * 64 + pB * 8);
            }
            #pragma unroll
            for (int i = 0; i < 4; ++i)
                #pragma unroll
                for (int jj = 0; jj < 4; ++jj)
                    acc[i][jj] = __builtin_amdgcn_mfma_f32_16x16x32_bf16(a[i], b[jj], acc[i][jj], 0, 0, 0);
        }
    }

    float bvv[4];
    #pragma unroll
    for (int jj = 0; jj < 4; ++jj) bvv[jj] = bias[n0 + wn * 64 + jj * 16 + l16];
    #pragma unroll
    for (int i = 0; i < 4; ++i)
        #pragma unroll
        for (int jj = 0; jj < 4; ++jj) {
            const int n = n0 + wn * 64 + jj * 16 + l16;
            #pragma unroll
            for (int r = 0; r < 4; ++r) {
                const int m = m0 + wm * 64 + i * 16 + quad * 4 + r;
                out[(size_t)m * DD + n] = acc[i][jj][r] + bvv[jj];
            }
        }
}

// ---------------- flash-style MFMA attention --------------------------------
// grid (192, 8): x = h + 12*b, y = qt  (qt slowest -> same-(b,h) blocks on one XCD)
// p = la * exp(s/8 - m): softmax(log la + s/8) without the log; /8 folded
// into the exp via fma.
__global__ __launch_bounds__(256) void attn_mfma(
    const short* __restrict__ Q, const short* __restrict__ K,
    const short* __restrict__ Vt, const short* __restrict__ LA,
    short* __restrict__ out)
{
    __shared__ short Ks[64 * 64];
    __shared__ short Vs[64 * 64];
    __shared__ short bs16[64 * 68];
    __shared__ short Ps[4][16 * 64];

    const int h = blockIdx.x % 12, b = blockIdx.x / 12;
    const int qt = blockIdx.y;
    const int tid = threadIdx.x;
    const int w = tid >> 6, lane = tid & 63;
    const int quad = lane >> 4, l16 = lane & 15;
    const int q0 = qt * 64;
    const size_t bh = (size_t)b * HH + h;

    const int qr = q0 + w * 16 + l16;
    const bf8_t aq0 = *(const bf8_t*)(Q + (bh * LL + qr) * DHH + quad * 8);
    const bf8_t aq1 = *(const bf8_t*)(Q + (bh * LL + qr) * DHH + quad * 8 + 32);

    f4_t o[4];
    #pragma unroll
    for (int dj = 0; dj < 4; ++dj) o[dj] = (f4_t){0.f, 0.f, 0.f, 0.f};
    float m_row[4], l_row[4];
    #pragma unroll
    for (int r = 0; r < 4; ++r) { m_row[r] = -1e30f; l_row[r] = 0.f; }

    const short* Kg = K  + bh * LL * DHH;
    const short* Vg = Vt + bh * DHH * LL;
    const short* Bg = LA + (bh * LL + q0) * LL;

    const int srow = tid >> 2;
    const int cb   = (tid & 3) * 2;
    const int sw   = srow & 7;

    for (int t0 = 0; t0 < LL; t0 += 64) {
        __syncthreads();
        {
            const short* src = Kg + (size_t)(t0 + srow) * DHH + cb * 8;
            *(bf8_t*)(Ks + srow * 64 + ((cb ^ sw) * 8))       = *(const bf8_t*)(src);
            *(bf8_t*)(Ks + srow * 64 + (((cb + 1) ^ sw) * 8)) = *(const bf8_t*)(src + 8);
        }
        {
            const short* src = Vg + (size_t)srow * LL + t0 + cb * 8;
            *(bf8_t*)(Vs + srow * 64 + ((cb ^ sw) * 8))       = *(const bf8_t*)(src);
            *(bf8_t*)(Vs + srow * 64 + (((cb + 1) ^ sw) * 8)) = *(const bf8_t*)(src + 8);
        }
        {
            const int l = tid >> 2, ts = (tid & 3) * 16;
            const short* src = Bg + (size_t)l * LL + t0 + ts;
            #pragma unroll
            for (int i = 0; i < 4; ++i)
                *(short4*)(bs16 + l * 68 + ts + i * 4) = *(const short4*)(src + i * 4);
        }
        __syncthreads();

        // ---- S = Q K^T ----
        f4_t sv[4];
        #pragma unroll
        for (int j = 0; j < 4; ++j) {
            const int rB = j * 16 + l16;
            const int x = rB & 7;
            const bf8_t b0 = *(const bf8_t*)(Ks + rB * 64 + ((quad ^ x) * 8));
            const bf8_t b1 = *(const bf8_t*)(Ks + rB * 64 + (((quad + 4) ^ x) * 8));
            f4_t c = (f4_t){0.f, 0.f, 0.f, 0.f};
            c = __builtin_amdgcn_mfma_f32_16x16x32_bf16(aq0, b0, c, 0, 0, 0);
            c = __builtin_amdgcn_mfma_f32_16x16x32_bf16(aq1, b1, c, 0, 0, 0);
            sv[j] = c;
        }

        // ---- online softmax: p = la * exp(s/8 - m), m tracked over s/8 ----
        #pragma unroll
        for (int r = 0; r < 4; ++r) {
            const int lrel = w * 16 + quad * 4 + r;
            float mx = fmaxf(fmaxf(sv[0][r], sv[1][r]), fmaxf(sv[2][r], sv[3][r]));
            mx = fmaxf(mx, __shfl_xor(mx, 1, 16));
            mx = fmaxf(mx, __shfl_xor(mx, 2, 16));
            mx = fmaxf(mx, __shfl_xor(mx, 4, 16));
            mx = fmaxf(mx, __shfl_xor(mx, 8, 16));
            const float mn = fmaxf(m_row[r], mx * 0.125f);
            const float al = __expf(m_row[r] - mn);
            m_row[r] = mn;
            float rs = 0.f;
            #pragma unroll
            for (int j = 0; j < 4; ++j) {
                const float lav = bf2f(bs16[lrel * 68 + j * 16 + l16]);
                const float p = lav * __expf(__builtin_fmaf(sv[j][r], 0.125f, -mn));
                sv[j][r] = p;
                rs += p;
            }
            rs += __shfl_xor(rs, 1, 16);
            rs += __shfl_xor(rs, 2, 16);
            rs += __shfl_xor(rs, 4, 16);
            rs += __shfl_xor(rs, 8, 16);
            l_row[r] = l_row[r] * al + rs;
            #pragma unroll
            for (int dj = 0; dj < 4; ++dj) o[dj][r] *= al;
        }
        // ---- P: C-layout -> swizzled LDS -> A-layout ----
        short* Pw = Ps[w];
        #pragma unroll
        for (int r = 0; r < 4; ++r) {
            const int rp = quad * 4 + r, rp7 = rp & 7;
            #pragma unroll
            for (int j = 0; j < 4; ++j) {
                const int t = j * 16 + l16;
                Pw[rp * 64 + (((t >> 3) ^ rp7) * 8) + (t & 7)] = f2bf(sv[j][r]);
            }
        }
        const int m7 = l16 & 7;
        const bf8_t ap0 = *(const bf8_t*)(Pw + l16 * 64 + ((quad ^ m7) * 8));
        const bf8_t ap1 = *(const bf8_t*)(Pw + l16 * 64 + (((quad + 4) ^ m7) * 8));
        #pragma unroll
        for (int dj = 0; dj < 4; ++dj) {
            const int rB = dj * 16 + l16;
            const int x = rB & 7;
            const bf8_t b0 = *(const bf8_t*)(Vs + rB * 64 + ((quad ^ x) * 8));
            const bf8_t b1 = *(const bf8_t*)(Vs + rB * 64 + (((quad + 4) ^ x) * 8));
            o[dj] = __builtin_amdgcn_mfma_f32_16x16x32_bf16(ap0, b0, o[dj], 0, 0, 0);
            o[dj] = __builtin_amdgcn_mfma_f32_16x16x32_bf16(ap1, b1, o[dj], 0, 0, 0);
        }
    }

    #pragma unroll
    for (int r = 0; r < 4; ++r) {
        const int l = q0 + w * 16 + quad * 4 + r;
        const float inv = 1.f / l_row[r];
        short* op = out + ((size_t)b * LL + l) * DD + h * DHH;
        #pragma unroll
        for (int dj = 0; dj < 4; ++dj)
            op[dj * 16 + l16] = f2bf(o[dj][r] * inv);
    }
}

// ---------------- residual + LayerNorm --------------------------------------
__global__ __launch_bounds__(256) void ln_kernel(
    const float* __restrict__ x, const float* __restrict__ tgt,
    const float* __restrict__ g, const float* __restrict__ bta,
    float* __restrict__ out)
{
    const int row = blockIdx.x;
    const int tid = threadIdx.x;
    __shared__ float red[4];

    const float* xp = x + (size_t)row * DD;
    const float* tp = tgt + (size_t)row * DD;

    float vals[3];
    float s = 0.f;
    #pragma unroll
    for (int i = 0; i < 3; ++i) {
        const float v = xp[tid + i * 256] + tp[tid + i * 256];
        vals[i] = v;
        s += v;
    }
    s = block_sum(s, red, tid);
    const float mu = s * (1.f / 768.f);

    float vs = 0.f;
    #pragma unroll
    for (int i = 0; i < 3; ++i) {
        const float dv = vals[i] - mu;
        vs += dv * dv;
    }
    vs = block_sum(vs, red, tid);
    const float rstd = rsqrtf(vs * (1.f / 768.f) + LN_EPS);

    #pragma unroll
    for (int i = 0; i < 3; ++i) {
        const int cidx = tid + i * 256;
        out[(size_t)row * DD + cidx] = g[cidx] * (vals[i] - mu) * rstd + bta[cidx];
    }
}

// ---------------- launch -----------------------------------------------------
extern "C" void kernel_launch(void* const* d_in, const int* in_sizes, int n_in,
                              void* d_out, int out_size, void* d_ws, size_t ws_size,
                              hipStream_t stream) {
    const float* tgt   = (const float*)d_in[0];
    const float* qpos  = (const float*)d_in[1];
    const float* ploc  = (const float*)d_in[2];
    const float* Wq    = (const float*)d_in[3];
    const float* bq    = (const float*)d_in[4];
    const float* Wk    = (const float*)d_in[5];
    const float* bk    = (const float*)d_in[6];
    const float* Wv    = (const float*)d_in[7];
    const float* bv    = (const float*)d_in[8];
    const float* Wo    = (const float*)d_in[9];
    const float* bo    = (const float*)d_in[10];
    const float* Wloc  = (const float*)d_in[11];
    const float* bloc  = (const float*)d_in[12];
    const float* ln_g  = (const float*)d_in[13];
    const float* ln_b  = (const float*)d_in[14];

    const size_t NQ = (size_t)MM * DD;           // 6291456
    const size_t NW = (size_t)DD * DD;           // 589824

    short* qb   = (short*)d_ws;
    short* kb   = qb  + NQ;
    short* vtb  = kb  + NQ;
    short* aob  = vtb + NQ;
    short* aqk  = aob + NQ;
    short* av   = aqk + NQ;
    float* pbuf = (float*)aqk;                   // alias (aqk,av dead by then)
    short* wqt  = av + NQ;
    short* wkt  = wqt + NW;
    short* wvt  = wkt + NW;
    short* wot  = wvt + NW;
    short* lab  = wot + NW;

    prep_kernel<<<3648, 256, 0, stream>>>(tgt, qpos, Wq, Wk, Wv, Wo,
                                          aqk, av, wqt, wkt, wvt, wot);

    qkv_la<<<3200, 256, 0, stream>>>(aqk, av, wqt, bq, qb,
                                     wkt, bk, kb, wvt, bv, vtb,
                                     ploc, Wloc, bloc, lab);

    attn_mfma<<<dim3(192, 8), 256, 0, stream>>>(qb, kb, vtb, lab, aob);

    gemm_o<<<dim3(6, 64), 256, 0, stream>>>(aob, wot, bo, pbuf);

    ln_kernel<<<MM, 256, 0, stream>>>(pbuf, tgt, ln_g, ln_b, (float*)d_out);
}